// Round 1
// baseline (137.338 us; speedup 1.0000x reference)
//
#include <hip/hip_runtime.h>
#include <cmath>

// Encoder_conv2: 5-level multires feature encoder.
//   Stage A: depthwise 3x3 conv (+tanh) over tiny tables (15648 floats total)
//   Stage B: bilinear grid-sample at 1e6 points, 2 cells, 4 channels, 5 levels
// Table layout after conv: [level][cell][y][x][c] with c(=4) contiguous so a
// corner fetch is a single float4 (ds_read_b128 from LDS).

#define NTH 256
#define PPT 4   // points per thread in the sampling kernel

constexpr int TOT = 15648;      // total floats in the conv'd table (sum 8*r^2)
// per-level float offsets (sizes 8*r^2: 512,1152,3200,2592,8192)
#define OFF0 0
#define OFF1 512
#define OFF2 1664
#define OFF3 4864
#define OFF4 7456

// ---------------- Stage A: depthwise conv 3x3 (SAME, cross-corr) + tanh ----
template<int R>
__device__ __forceinline__ void conv_level(const float* __restrict__ F,
                                           const float* __restrict__ w,
                                           float* __restrict__ dst,
                                           int tid, int nth)
{
    const int n = 8 * R * R;              // 2 cells * 4 ch * R * R
    for (int i = tid; i < n; i += nth) {
        int c    = i & 3;
        int pos  = i >> 2;
        int cell = (pos >= R * R) ? 1 : 0;
        int rem  = pos - cell * R * R;
        int yy   = rem / R;               // R is compile-time: magic-mul
        int xx   = rem - yy * R;
        const float* Fc = F + (cell * 4 + c) * R * R;
        float acc = 0.f;
#pragma unroll
        for (int ky = 0; ky < 3; ++ky) {
#pragma unroll
            for (int kx = 0; kx < 3; ++kx) {
                int sy = yy + ky - 1, sx = xx + kx - 1;
                if ((unsigned)sy < (unsigned)R && (unsigned)sx < (unsigned)R)
                    acc += w[c * 9 + ky * 3 + kx] * Fc[sy * R + sx];
            }
        }
        dst[cell * (R * R * 4) + (yy * R + xx) * 4 + c] = tanhf(acc);
    }
}

__global__ void conv_kernel(const float* __restrict__ F0, const float* __restrict__ F1,
                            const float* __restrict__ F2, const float* __restrict__ F3,
                            const float* __restrict__ F4, const float* __restrict__ w,
                            float* __restrict__ tab)
{
    int tid = blockIdx.x * NTH + threadIdx.x;
    int nth = gridDim.x * NTH;
    conv_level<8 >(F0, w, tab + OFF0, tid, nth);
    conv_level<12>(F1, w, tab + OFF1, tid, nth);
    conv_level<20>(F2, w, tab + OFF2, tid, nth);
    conv_level<18>(F3, w, tab + OFF3, tid, nth);
    conv_level<32>(F4, w, tab + OFF4, tid, nth);
}

// ---------------- Stage B: bilinear sampling --------------------------------
template<int R>
__device__ __forceinline__ float4 sample_level(const float* __restrict__ lt,
                                               float px, float py)
{
    // ix = (gx+1)*0.5*(R-1) with gx = 2x-1  ==  x*(R-1)
    float fx = px * (float)(R - 1);
    float fy = py * (float)(R - 1);
    float4 acc = make_float4(0.f, 0.f, 0.f, 0.f);
#pragma unroll
    for (int cell = 0; cell < 2; ++cell) {
        float ixc = fx + 0.5f * (float)cell;   // off = cell/n_cells
        float iyc = fy + 0.5f * (float)cell;
        float fx0 = floorf(ixc);
        float fy0 = floorf(iyc);
        float wx = ixc - fx0;
        float wy = iyc - fy0;
        int ix0 = (int)fx0;
        int iy0 = (int)fy0;
        int x0 = min(max(ix0,     0), R - 1);
        int x1 = min(max(ix0 + 1, 0), R - 1);
        int y0 = min(max(iy0,     0), R - 1);
        int y1 = min(max(iy0 + 1, 0), R - 1);
        const float* cb = lt + cell * (R * R * 4);
        float4 nw = *(const float4*)(cb + (y0 * R + x0) * 4);
        float4 ne = *(const float4*)(cb + (y0 * R + x1) * 4);
        float4 sw = *(const float4*)(cb + (y1 * R + x0) * 4);
        float4 se = *(const float4*)(cb + (y1 * R + x1) * 4);
        float u = 1.f - wx, v = 1.f - wy;
        float wnw = u * v, wne = wx * v, wsw = u * wy, wse = wx * wy;
        acc.x += wnw * nw.x + wne * ne.x + wsw * sw.x + wse * se.x;
        acc.y += wnw * nw.y + wne * ne.y + wsw * sw.y + wse * se.y;
        acc.z += wnw * nw.z + wne * ne.z + wsw * sw.z + wse * se.z;
        acc.w += wnw * nw.w + wne * ne.w + wsw * sw.w + wse * se.w;
    }
    return acc;
}

__device__ __forceinline__ void sample_body(const float* lds,
                                            const float* __restrict__ x,
                                            const float* __restrict__ y,
                                            float* __restrict__ out, int npts)
{
    int p0 = blockIdx.x * (NTH * PPT) + threadIdx.x;
    for (int k = 0; k < PPT; ++k) {
        int p = p0 + k * NTH;
        bool ok = p < npts;
        int pc = ok ? p : 0;
        float px = x[pc];
        float py = y[pc];
        float4 r0 = sample_level<8 >(lds + OFF0, px, py);
        float4 r1 = sample_level<12>(lds + OFF1, px, py);
        float4 r2 = sample_level<20>(lds + OFF2, px, py);
        float4 r3 = sample_level<18>(lds + OFF3, px, py);
        float4 r4 = sample_level<32>(lds + OFF4, px, py);
        if (ok) {
            // out row = 20 floats (80 B) -> 16B aligned for every p
            float4* op = (float4*)(out + (size_t)p * 20);
            op[0] = r0; op[1] = r1; op[2] = r2; op[3] = r3; op[4] = r4;
        }
    }
}

__global__ __launch_bounds__(NTH, 2) void sample_kernel(const float* __restrict__ x,
                                                        const float* __restrict__ y,
                                                        const float* __restrict__ tab,
                                                        float* __restrict__ out, int npts)
{
    __shared__ __align__(16) float lds[TOT];   // 62,592 B -> 2 blocks/CU
    const float4* g4 = (const float4*)tab;
    float4* l4 = (float4*)lds;
    for (int i = threadIdx.x; i < TOT / 4; i += NTH)
        l4[i] = g4[i];
    __syncthreads();
    sample_body(lds, x, y, out, npts);
}

// Fallback if workspace is too small: conv recomputed per block into LDS.
__global__ __launch_bounds__(NTH, 2) void fused_kernel(const float* __restrict__ x,
                                                       const float* __restrict__ y,
                                                       const float* __restrict__ F0,
                                                       const float* __restrict__ F1,
                                                       const float* __restrict__ F2,
                                                       const float* __restrict__ F3,
                                                       const float* __restrict__ F4,
                                                       const float* __restrict__ w,
                                                       float* __restrict__ out, int npts)
{
    __shared__ __align__(16) float lds[TOT];
    conv_level<8 >(F0, w, lds + OFF0, threadIdx.x, NTH);
    conv_level<12>(F1, w, lds + OFF1, threadIdx.x, NTH);
    conv_level<20>(F2, w, lds + OFF2, threadIdx.x, NTH);
    conv_level<18>(F3, w, lds + OFF3, threadIdx.x, NTH);
    conv_level<32>(F4, w, lds + OFF4, threadIdx.x, NTH);
    __syncthreads();
    sample_body(lds, x, y, out, npts);
}

extern "C" void kernel_launch(void* const* d_in, const int* in_sizes, int n_in,
                              void* d_out, int out_size, void* d_ws, size_t ws_size,
                              hipStream_t stream)
{
    const float* x  = (const float*)d_in[0];
    const float* y  = (const float*)d_in[1];
    const float* w  = (const float*)d_in[2];
    const float* F0 = (const float*)d_in[3];
    const float* F1 = (const float*)d_in[4];
    const float* F2 = (const float*)d_in[5];
    const float* F3 = (const float*)d_in[6];
    const float* F4 = (const float*)d_in[7];
    float* out = (float*)d_out;
    int npts = in_sizes[0];

    int nb = (npts + NTH * PPT - 1) / (NTH * PPT);

    if (ws_size >= (size_t)TOT * sizeof(float)) {
        float* tab = (float*)d_ws;
        conv_kernel<<<(TOT + NTH - 1) / NTH, NTH, 0, stream>>>(F0, F1, F2, F3, F4, w, tab);
        sample_kernel<<<nb, NTH, 0, stream>>>(x, y, tab, out, npts);
    } else {
        fused_kernel<<<nb, NTH, 0, stream>>>(x, y, F0, F1, F2, F3, F4, w, out, npts);
    }
}

// Round 2
// 124.823 us; speedup vs baseline: 1.1003x; 1.1003x over previous
//
#include <hip/hip_runtime.h>
#include <cmath>

// Encoder_conv2: 5-level multires feature encoder.
//   Stage A: depthwise 3x3 conv (+tanh) over tiny tables (15648 floats total)
//   Stage B: bilinear grid-sample at 1e6 points, 2 cells, 4 channels, 5 levels
// Table layout after conv: [level][cell][y][x][c] with c(=4) contiguous so a
// corner fetch is a single float4 (ds_read_b128 from LDS).
//
// R2: 512-thread blocks (__launch_bounds__(512,4)) -> 2 blocks/CU despite the
// 62.5 KB LDS table = 16 waves/CU (was 8). Sampling is LDS-throughput bound
// (40 ds_read_b128/point); occupancy is the lever, not HBM.

#define NTH 512
#define PPT 4   // points per thread in the sampling kernel

constexpr int TOT = 15648;      // total floats in the conv'd table (sum 8*r^2)
// per-level float offsets (sizes 8*r^2: 512,1152,3200,2592,8192)
#define OFF0 0
#define OFF1 512
#define OFF2 1664
#define OFF3 4864
#define OFF4 7456

// ---------------- Stage A: depthwise conv 3x3 (SAME, cross-corr) + tanh ----
template<int R>
__device__ __forceinline__ void conv_level(const float* __restrict__ F,
                                           const float* __restrict__ w,
                                           float* __restrict__ dst,
                                           int tid, int nth)
{
    const int n = 8 * R * R;              // 2 cells * 4 ch * R * R
    for (int i = tid; i < n; i += nth) {
        int c    = i & 3;
        int pos  = i >> 2;
        int cell = (pos >= R * R) ? 1 : 0;
        int rem  = pos - cell * R * R;
        int yy   = rem / R;               // R is compile-time: magic-mul
        int xx   = rem - yy * R;
        const float* Fc = F + (cell * 4 + c) * R * R;
        float acc = 0.f;
#pragma unroll
        for (int ky = 0; ky < 3; ++ky) {
#pragma unroll
            for (int kx = 0; kx < 3; ++kx) {
                int sy = yy + ky - 1, sx = xx + kx - 1;
                if ((unsigned)sy < (unsigned)R && (unsigned)sx < (unsigned)R)
                    acc += w[c * 9 + ky * 3 + kx] * Fc[sy * R + sx];
            }
        }
        dst[cell * (R * R * 4) + (yy * R + xx) * 4 + c] = tanhf(acc);
    }
}

__global__ void conv_kernel(const float* __restrict__ F0, const float* __restrict__ F1,
                            const float* __restrict__ F2, const float* __restrict__ F3,
                            const float* __restrict__ F4, const float* __restrict__ w,
                            float* __restrict__ tab)
{
    int tid = blockIdx.x * blockDim.x + threadIdx.x;
    int nth = gridDim.x * blockDim.x;
    conv_level<8 >(F0, w, tab + OFF0, tid, nth);
    conv_level<12>(F1, w, tab + OFF1, tid, nth);
    conv_level<20>(F2, w, tab + OFF2, tid, nth);
    conv_level<18>(F3, w, tab + OFF3, tid, nth);
    conv_level<32>(F4, w, tab + OFF4, tid, nth);
}

// ---------------- Stage B: bilinear sampling --------------------------------
template<int R>
__device__ __forceinline__ float4 sample_level(const float* __restrict__ lt,
                                               float px, float py)
{
    // ix = (gx+1)*0.5*(R-1) with gx = 2x-1  ==  x*(R-1)
    float fx = px * (float)(R - 1);
    float fy = py * (float)(R - 1);
    float4 acc = make_float4(0.f, 0.f, 0.f, 0.f);
#pragma unroll
    for (int cell = 0; cell < 2; ++cell) {
        float ixc = fx + 0.5f * (float)cell;   // off = cell/n_cells
        float iyc = fy + 0.5f * (float)cell;
        float fx0 = floorf(ixc);
        float fy0 = floorf(iyc);
        float wx = ixc - fx0;
        float wy = iyc - fy0;
        int ix0 = (int)fx0;
        int iy0 = (int)fy0;
        int x0 = min(max(ix0,     0), R - 1);
        int x1 = min(max(ix0 + 1, 0), R - 1);
        int y0 = min(max(iy0,     0), R - 1);
        int y1 = min(max(iy0 + 1, 0), R - 1);
        const float* cb = lt + cell * (R * R * 4);
        float4 nw = *(const float4*)(cb + (y0 * R + x0) * 4);
        float4 ne = *(const float4*)(cb + (y0 * R + x1) * 4);
        float4 sw = *(const float4*)(cb + (y1 * R + x0) * 4);
        float4 se = *(const float4*)(cb + (y1 * R + x1) * 4);
        float u = 1.f - wx, v = 1.f - wy;
        float wnw = u * v, wne = wx * v, wsw = u * wy, wse = wx * wy;
        acc.x = fmaf(wnw, nw.x, acc.x); acc.x = fmaf(wne, ne.x, acc.x);
        acc.x = fmaf(wsw, sw.x, acc.x); acc.x = fmaf(wse, se.x, acc.x);
        acc.y = fmaf(wnw, nw.y, acc.y); acc.y = fmaf(wne, ne.y, acc.y);
        acc.y = fmaf(wsw, sw.y, acc.y); acc.y = fmaf(wse, se.y, acc.y);
        acc.z = fmaf(wnw, nw.z, acc.z); acc.z = fmaf(wne, ne.z, acc.z);
        acc.z = fmaf(wsw, sw.z, acc.z); acc.z = fmaf(wse, se.z, acc.z);
        acc.w = fmaf(wnw, nw.w, acc.w); acc.w = fmaf(wne, ne.w, acc.w);
        acc.w = fmaf(wsw, sw.w, acc.w); acc.w = fmaf(wse, se.w, acc.w);
    }
    return acc;
}

__device__ __forceinline__ void sample_body(const float* lds,
                                            const float* __restrict__ x,
                                            const float* __restrict__ y,
                                            float* __restrict__ out, int npts)
{
    int p0 = blockIdx.x * (NTH * PPT) + threadIdx.x;
    // Prefetch all PPT point coords first so the global loads overlap.
    float pxs[PPT], pys[PPT];
#pragma unroll
    for (int k = 0; k < PPT; ++k) {
        int p = p0 + k * NTH;
        int pc = (p < npts) ? p : 0;
        pxs[k] = x[pc];
        pys[k] = y[pc];
    }
    for (int k = 0; k < PPT; ++k) {
        int p = p0 + k * NTH;
        float px = pxs[k];
        float py = pys[k];
        float4 r0 = sample_level<8 >(lds + OFF0, px, py);
        float4 r1 = sample_level<12>(lds + OFF1, px, py);
        float4 r2 = sample_level<20>(lds + OFF2, px, py);
        float4 r3 = sample_level<18>(lds + OFF3, px, py);
        float4 r4 = sample_level<32>(lds + OFF4, px, py);
        if (p < npts) {
            // out row = 20 floats (80 B) -> 16B aligned for every p
            float4* op = (float4*)(out + (size_t)p * 20);
            op[0] = r0; op[1] = r1; op[2] = r2; op[3] = r3; op[4] = r4;
        }
    }
}

__global__ __launch_bounds__(NTH, 4) void sample_kernel(const float* __restrict__ x,
                                                        const float* __restrict__ y,
                                                        const float* __restrict__ tab,
                                                        float* __restrict__ out, int npts)
{
    __shared__ __align__(16) float lds[TOT];   // 62,592 B -> 2 blocks/CU
    const float4* g4 = (const float4*)tab;
    float4* l4 = (float4*)lds;
    for (int i = threadIdx.x; i < TOT / 4; i += NTH)
        l4[i] = g4[i];
    __syncthreads();
    sample_body(lds, x, y, out, npts);
}

// Fallback if workspace is too small: conv recomputed per block into LDS.
__global__ __launch_bounds__(NTH, 4) void fused_kernel(const float* __restrict__ x,
                                                       const float* __restrict__ y,
                                                       const float* __restrict__ F0,
                                                       const float* __restrict__ F1,
                                                       const float* __restrict__ F2,
                                                       const float* __restrict__ F3,
                                                       const float* __restrict__ F4,
                                                       const float* __restrict__ w,
                                                       float* __restrict__ out, int npts)
{
    __shared__ __align__(16) float lds[TOT];
    conv_level<8 >(F0, w, lds + OFF0, threadIdx.x, NTH);
    conv_level<12>(F1, w, lds + OFF1, threadIdx.x, NTH);
    conv_level<20>(F2, w, lds + OFF2, threadIdx.x, NTH);
    conv_level<18>(F3, w, lds + OFF3, threadIdx.x, NTH);
    conv_level<32>(F4, w, lds + OFF4, threadIdx.x, NTH);
    __syncthreads();
    sample_body(lds, x, y, out, npts);
}

extern "C" void kernel_launch(void* const* d_in, const int* in_sizes, int n_in,
                              void* d_out, int out_size, void* d_ws, size_t ws_size,
                              hipStream_t stream)
{
    const float* x  = (const float*)d_in[0];
    const float* y  = (const float*)d_in[1];
    const float* w  = (const float*)d_in[2];
    const float* F0 = (const float*)d_in[3];
    const float* F1 = (const float*)d_in[4];
    const float* F2 = (const float*)d_in[5];
    const float* F3 = (const float*)d_in[6];
    const float* F4 = (const float*)d_in[7];
    float* out = (float*)d_out;
    int npts = in_sizes[0];

    int nb = (npts + NTH * PPT - 1) / (NTH * PPT);

    if (ws_size >= (size_t)TOT * sizeof(float)) {
        float* tab = (float*)d_ws;
        conv_kernel<<<(TOT + 255) / 256, 256, 0, stream>>>(F0, F1, F2, F3, F4, w, tab);
        sample_kernel<<<nb, NTH, 0, stream>>>(x, y, tab, out, npts);
    } else {
        fused_kernel<<<nb, NTH, 0, stream>>>(x, y, F0, F1, F2, F3, F4, w, out, npts);
    }
}